// Round 10
// baseline (36.775 us; speedup 1.0000x reference)
//
#include <hip/hip_runtime.h>

typedef float  f32x4 __attribute__((ext_vector_type(4)));
typedef short  s16x8 __attribute__((ext_vector_type(8)));
typedef _Float16 h2 __attribute__((ext_vector_type(2)));
typedef unsigned short u16;
typedef u16 u16x4 __attribute__((ext_vector_type(4)));

#define N_DIMS 1024
#define N_OSC  352
#define BATCH  4096
#define EPSV   1e-6f
#define INV2PI 0.15915494309189535f

// ---------------- conversion f32 -> bf16 (unchanged R7) ----------------
__device__ __forceinline__ u16 f2bf(float f){
  unsigned u = __builtin_bit_cast(unsigned, f);
  u += 0x7FFFu + ((u >> 16) & 1u);   // round-to-nearest-even
  return (u16)(u >> 16);
}
__device__ __forceinline__ float bf2f(unsigned h){
  return __builtin_bit_cast(float, h << 16);
}

#define NX4 1048576   // 4096*1024/4
#define NW4 90112     // 352*1024/4 (per weight matrix)

__global__ __launch_bounds__(256) void convert_k(const f32x4* __restrict__ x,
    const f32x4* __restrict__ wp, const f32x4* __restrict__ wa,
    u16x4* __restrict__ xb, u16x4* __restrict__ wb){
  int i = blockIdx.x * 256 + threadIdx.x;
  f32x4 v; u16x4* dst;
  if (i < NX4) { v = x[i]; dst = xb + i; }
  else {
    int j = i - NX4;
    v = (j < NW4) ? wp[j] : wa[j - NW4];
    dst = wb + j;
  }
  u16x4 r;
  r[0]=f2bf(v[0]); r[1]=f2bf(v[1]); r[2]=f2bf(v[2]); r[3]=f2bf(v[3]);
  *dst = r;
}

// ---------------- GEMM v4: 1 wave/block, 64x64 wave tile ----------------
// Grid 704 (XCD-bijective). Per kt (K=64): 16 ds_read_b128 feed 32 MFMA
// (0.5 reads/MFMA vs 1.0 in R7) -> cuts the per-CU LDS-throughput bound.
// No barriers (single wave); 3-buffer global_load_lds pipeline with exact
// s_waitcnt vmcnt(16): STAGE(kt+2) issued AFTER COMPUTE(kt), so the buffer
// it overwrites was last read a full compute-phase ago.
__device__ __forceinline__ void gload16(const u16* g, u16* l){
  __builtin_amdgcn_global_load_lds(
      (const __attribute__((address_space(1))) unsigned int*)(g),
      (__attribute__((address_space(3))) unsigned int*)(l), 16, 0, 0);
}

__global__ __launch_bounds__(64) void gemm_k(const u16* __restrict__ xb,
    const u16* __restrict__ wb, u16* __restrict__ phase0, float* __restrict__ amp0){
  __shared__ u16 lds[3][8192];          // 48 KB: [buf][A 4096 u16 | B 4096 u16]
  const int l = threadIdx.x;

  // XCD-bijective swizzle: 704 = 8 x 88 (xcd = bid & 7)
  const int bid = blockIdx.x;
  const int xcd = bid & 7;
  const int r   = bid >> 3;
  const int mt  = xcd * 8 + r / 11;
  const int nt  = r % 11;
  const int m0  = mt * 64;
  const int n0  = nt * 64;

  // staging: issue i covers rows +8i; lane l -> row l>>3, slot l&7 (16B units);
  // T2 inverse-swizzled source slot (l&7)^(l>>3); row&7 == l>>3 for all issues.
  const int srow = l >> 3;
  const int scol = ((l & 7) ^ srow) * 8;
  const u16* ga = xb + (size_t)(m0 + srow) * N_DIMS + scol;
  const u16* gb = wb + (size_t)(n0 + srow) * N_DIMS + scol;

  #define STAGE(b, kt) { \
    _Pragma("unroll") \
    for (int i = 0; i < 8; i++){ \
      gload16(ga + (kt)*64 + i*8*N_DIMS, &lds[b][i*512]); \
      gload16(gb + (kt)*64 + i*8*N_DIMS, &lds[b][4096 + i*512]); } }

  const int rl = l & 15;
  const int q0 = l >> 4;          // k-quarter (8 elems)
  const int sx = rl & 7;          // frag row & 7 (mi*16 doesn't change it)

  f32x4 acc[4][4] = {};

  #define COMPUTE(b) { \
    s16x8 af[4][2], bf[4][2]; \
    _Pragma("unroll") \
    for (int mi = 0; mi < 4; mi++){ \
      const int row = mi*16 + rl; \
      af[mi][0] = *(const s16x8*)&lds[b][row*64 + ((q0 ^ sx) * 8)]; \
      af[mi][1] = *(const s16x8*)&lds[b][row*64 + (((4 + q0) ^ sx) * 8)]; \
    } \
    _Pragma("unroll") \
    for (int nj = 0; nj < 4; nj++){ \
      const int row = nj*16 + rl; \
      bf[nj][0] = *(const s16x8*)&lds[b][4096 + row*64 + ((q0 ^ sx) * 8)]; \
      bf[nj][1] = *(const s16x8*)&lds[b][4096 + row*64 + (((4 + q0) ^ sx) * 8)]; \
    } \
    _Pragma("unroll") \
    for (int ks = 0; ks < 2; ks++) \
    _Pragma("unroll") \
    for (int mi = 0; mi < 4; mi++) \
    _Pragma("unroll") \
    for (int nj = 0; nj < 4; nj++) \
      acc[mi][nj] = __builtin_amdgcn_mfma_f32_16x16x32_bf16(af[mi][ks], bf[nj][ks], acc[mi][nj], 0,0,0); }

  STAGE(0, 0)
  STAGE(1, 1)

  #pragma unroll
  for (int kt = 0; kt < 16; kt++){
    if (kt < 15) asm volatile("s_waitcnt vmcnt(16)" ::: "memory");  // kt's 16 loads done; kt+1's in flight
    else         asm volatile("s_waitcnt vmcnt(0)"  ::: "memory");
    COMPUTE(kt % 3)
    if (kt < 14) STAGE((kt + 2) % 3, kt + 2)
  }
  #undef STAGE
  #undef COMPUTE

  // C/D layout: col = lane&15, row = (lane>>4)*4 + reg
  #pragma unroll
  for (int nj = 0; nj < 4; nj++){
    const int n = n0 + nj*16 + rl;          // 352 is a multiple of 16 -> branch uniform per nj
    const bool isph = (n < N_OSC);
    #pragma unroll
    for (int mi = 0; mi < 4; mi++)
    #pragma unroll
    for (int rg = 0; rg < 4; rg++){
      const int m = m0 + mi*16 + q0*4 + rg;
      float v = acc[mi][nj][rg];
      if (isph){ float t = v * INV2PI; t -= floorf(t); phase0[(size_t)m*N_OSC + n] = f2bf(t); }
      else     { amp0[(size_t)m*N_OSC + (n - N_OSC)] = fmaxf(fabsf(v), EPSV); }
    }
  }
}

// ---------------- iteration kernel (R7 v2; phase0 now bf16) ----------------
__device__ __forceinline__ int ibc(h2 v){ return __builtin_bit_cast(int, v); }
__device__ __forceinline__ h2  hbc(int v){ return __builtin_bit_cast(h2, v); }

__device__ __forceinline__ h2 rowsum16(h2 x){
  int v = ibc(x);
  v = ibc(hbc(v) + hbc(__builtin_amdgcn_mov_dpp(v, 0x121, 0xF, 0xF, true))); // row_ror:1
  v = ibc(hbc(v) + hbc(__builtin_amdgcn_mov_dpp(v, 0x122, 0xF, 0xF, true))); // row_ror:2
  v = ibc(hbc(v) + hbc(__builtin_amdgcn_mov_dpp(v, 0x124, 0xF, 0xF, true))); // row_ror:4
  v = ibc(hbc(v) + hbc(__builtin_amdgcn_mov_dpp(v, 0x128, 0xF, 0xF, true))); // row_ror:8
  return hbc(v);
}

__device__ __forceinline__ void updp(h2& s, h2& c, h2 cA, h2 sA, h2 GS, h2 GC){
  h2 e  = c*GS - s*GC;        // eps (radians), |e| <= 0.02
  h2 s1 = s*cA + c*sA;
  h2 c1 = c*cA - s*sA;
  s = s1 + c1*e;
  c = c1 - s1*e;
}

__device__ __forceinline__ h2 splat2(_Float16 v){ h2 r; r[0]=v; r[1]=v; return r; }

__global__ __launch_bounds__(256) void iter_k(const u16* __restrict__ phase0,
                                              float* __restrict__ amp){
  const int tid = threadIdx.x;
  const int l   = tid & 63;
  const int g   = l & 15;
  const int row = blockIdx.x*16 + (tid>>6)*4 + (l>>4);
  const size_t rb = (size_t)row * N_OSC;

  const h2 cAd = splat2((_Float16)0.99211470f), sAd = splat2((_Float16)0.12533323f);
  const h2 cAt = splat2((_Float16)0.92977649f), sAt = splat2((_Float16)0.36812455f);
  const h2 cAg = splat2((_Float16)-0.80901699f), sAg = splat2((_Float16)0.58778525f);
  const h2 kd = splat2((_Float16)6.25e-4f);    // DT*COUPLING/32
  const h2 kt = splat2((_Float16)3.125e-4f);   // /64
  const h2 kg = splat2((_Float16)7.8125e-5f);  // /256

  h2 sD, cD, sT[2], cT[2], sG[8], cG[8];
  {
    const u16* pr = phase0 + rb;
    unsigned dw = *(const unsigned*)(pr + 2*g);          // 2 bf16
    uint2 tw    = *(const uint2*)(pr + 32 + 4*g);        // 4 bf16
    uint4 g0w   = *(const uint4*)(pr + 96 + 16*g);       // 8 bf16
    uint4 g1w   = *(const uint4*)(pr + 96 + 16*g + 8);   // 8 bf16
    #define SC2(dS, dC, i, p0, p1) { \
      dS[i][0] = (_Float16)__builtin_amdgcn_sinf(p0); \
      dS[i][1] = (_Float16)__builtin_amdgcn_sinf(p1); \
      dC[i][0] = (_Float16)__builtin_amdgcn_cosf(p0); \
      dC[i][1] = (_Float16)__builtin_amdgcn_cosf(p1); }
    {
      float d0 = bf2f(dw & 0xFFFFu), d1 = bf2f(dw >> 16);
      sD[0] = (_Float16)__builtin_amdgcn_sinf(d0);
      sD[1] = (_Float16)__builtin_amdgcn_sinf(d1);
      cD[0] = (_Float16)__builtin_amdgcn_cosf(d0);
      cD[1] = (_Float16)__builtin_amdgcn_cosf(d1);
    }
    SC2(sT, cT, 0, bf2f(tw.x & 0xFFFFu), bf2f(tw.x >> 16))
    SC2(sT, cT, 1, bf2f(tw.y & 0xFFFFu), bf2f(tw.y >> 16))
    SC2(sG, cG, 0, bf2f(g0w.x & 0xFFFFu), bf2f(g0w.x >> 16))
    SC2(sG, cG, 1, bf2f(g0w.y & 0xFFFFu), bf2f(g0w.y >> 16))
    SC2(sG, cG, 2, bf2f(g0w.z & 0xFFFFu), bf2f(g0w.z >> 16))
    SC2(sG, cG, 3, bf2f(g0w.w & 0xFFFFu), bf2f(g0w.w >> 16))
    SC2(sG, cG, 4, bf2f(g1w.x & 0xFFFFu), bf2f(g1w.x >> 16))
    SC2(sG, cG, 5, bf2f(g1w.y & 0xFFFFu), bf2f(g1w.y >> 16))
    SC2(sG, cG, 6, bf2f(g1w.z & 0xFFFFu), bf2f(g1w.z >> 16))
    SC2(sG, cG, 7, bf2f(g1w.w & 0xFFFFu), bf2f(g1w.w >> 16))
    #undef SC2
  }

  h2 PD, PT, PG;
  #define REDUCE { \
    h2 pd; pd[0] = sD[0]+sD[1]; pd[1] = cD[0]+cD[1]; \
    h2 ts = sT[0]+sT[1], tc = cT[0]+cT[1]; \
    h2 pt; pt[0] = ts[0]+ts[1]; pt[1] = tc[0]+tc[1]; \
    h2 gs = ((sG[0]+sG[1])+(sG[2]+sG[3]))+((sG[4]+sG[5])+(sG[6]+sG[7])); \
    h2 gc = ((cG[0]+cG[1])+(cG[2]+cG[3]))+((cG[4]+cG[5])+(cG[6]+cG[7])); \
    h2 pg; pg[0] = gs[0]+gs[1]; pg[1] = gc[0]+gc[1]; \
    PD = rowsum16(pd); PT = rowsum16(pt); PG = rowsum16(pg); }

  REDUCE

  float Pth = 1.f, Pga = 1.f, mPth = 1.f, mPga = 1.f;
  for (int t = 0; t < 32; t++){
    h2 gd = PD * kd, gt = PT * kt, gg = PG * kg;   // (k*S, k*C)
    h2 GSd = splat2(gd[0]), GCd = splat2(gd[1]);
    h2 GSt = splat2(gt[0]), GCt = splat2(gt[1]);
    h2 GSg = splat2(gg[0]), GCg = splat2(gg[1]);
    updp(sD, cD, cAd, sAd, GSd, GCd);
    updp(sT[0], cT[0], cAt, sAt, GSt, GCt);
    updp(sT[1], cT[1], cAt, sAt, GSt, GCt);
    #pragma unroll
    for (int i = 0; i < 8; i++) updp(sG[i], cG[i], cAg, sAg, GSg, GCg);
    REDUCE
    float Sd = (float)PD[0], Cd = (float)PD[1];
    float St = (float)PT[0], Ct = (float)PT[1];
    float ft = 1.f + 0.003f * Cd * __builtin_amdgcn_rsqf(Cd*Cd + Sd*Sd);
    float fg = 1.f + 0.003f * Ct * __builtin_amdgcn_rsqf(Ct*Ct + St*St);
    Pth *= ft; mPth = fminf(mPth, Pth);
    Pga *= fg; mPga = fminf(mPga, Pga);
  }
  #undef REDUCE

  const float cth = EPSV * Pth / mPth;
  const float cga = EPSV * Pga / mPga;
  {
    float4 a = *(const float4*)(amp + rb + 32 + 4*g);
    a.x = fmaxf(a.x*Pth, cth); a.y = fmaxf(a.y*Pth, cth);
    a.z = fmaxf(a.z*Pth, cth); a.w = fmaxf(a.w*Pth, cth);
    *(float4*)(amp + rb + 32 + 4*g) = a;
  }
  #pragma unroll
  for (int i = 0; i < 4; i++){
    float4 a = *(const float4*)(amp + rb + 96 + 16*g + 4*i);
    a.x = fmaxf(a.x*Pga, cga); a.y = fmaxf(a.y*Pga, cga);
    a.z = fmaxf(a.z*Pga, cga); a.w = fmaxf(a.w*Pga, cga);
    *(float4*)(amp + rb + 96 + 16*g + 4*i) = a;
  }
}

// ---------------- launch ----------------
extern "C" void kernel_launch(void* const* d_in, const int* in_sizes, int n_in,
                              void* d_out, int out_size, void* d_ws, size_t ws_size,
                              hipStream_t stream){
  const float* x  = (const float*)d_in[0];
  const float* wp = (const float*)d_in[1];
  const float* wa = (const float*)d_in[2];
  float* out = (float*)d_out;
  char* ws = (char*)d_ws;
  u16* xb  = (u16*)(ws);                    // 8,388,608 B
  u16* wb  = (u16*)(ws + 8388608);          // 1,441,792 B
  u16* phase0 = (u16*)(ws + 9830400);       // 2,883,584 B (bf16)

  convert_k<<<4800, 256, 0, stream>>>((const f32x4*)x, (const f32x4*)wp, (const f32x4*)wa,
                                      (u16x4*)xb, (u16x4*)wb);
  gemm_k<<<704, 64, 0, stream>>>(xb, wb, phase0, out);
  iter_k<<<256, 256, 0, stream>>>(phase0, out);
}

// Round 11
// 32.137 us; speedup vs baseline: 1.1443x; 1.1443x over previous
//
#include <hip/hip_runtime.h>

typedef float  f32x4 __attribute__((ext_vector_type(4)));
typedef short  s16x8 __attribute__((ext_vector_type(8)));
typedef _Float16 h2 __attribute__((ext_vector_type(2)));
typedef unsigned short u16;
typedef u16 u16x4 __attribute__((ext_vector_type(4)));

#define N_DIMS 1024
#define N_OSC  352
#define BATCH  4096
#define EPSV   1e-6f
#define INV2PI 0.15915494309189535f

// ---------------- conversion f32 -> bf16 (R7) ----------------
__device__ __forceinline__ u16 f2bf(float f){
  unsigned u = __builtin_bit_cast(unsigned, f);
  u += 0x7FFFu + ((u >> 16) & 1u);   // round-to-nearest-even
  return (u16)(u >> 16);
}
__device__ __forceinline__ float bf2f(unsigned h){
  return __builtin_bit_cast(float, h << 16);
}

#define NX4 1048576   // 4096*1024/4
#define NW4 90112     // 352*1024/4 (per weight matrix)

__global__ __launch_bounds__(256) void convert_k(const f32x4* __restrict__ x,
    const f32x4* __restrict__ wp, const f32x4* __restrict__ wa,
    u16x4* __restrict__ xb, u16x4* __restrict__ wb){
  int i = blockIdx.x * 256 + threadIdx.x;
  f32x4 v; u16x4* dst;
  if (i < NX4) { v = x[i]; dst = xb + i; }
  else {
    int j = i - NX4;
    v = (j < NW4) ? wp[j] : wa[j - NW4];
    dst = wb + j;
  }
  u16x4 r;
  r[0]=f2bf(v[0]); r[1]=f2bf(v[1]); r[2]=f2bf(v[2]); r[3]=f2bf(v[3]);
  *dst = r;
}

// ---------------- GEMM: C[4096][704] = x @ [Wp;Wa]^T (R7 structure) ----------------
// BM=BN=BK=64, 4 waves (2x2), wave tile 32x32 via 16x16x32 MFMA acc[2][2].
// LDS double-buffered 32 KB, global_load_lds width=16 staging, T2 swizzle via
// inverse-swizzled global source. XCD-bijective block swizzle (704 = 8 x 88).
// phase0 written as bf16 (halves its write+read bytes; error <= 0.002 rev).
__device__ __forceinline__ void gload16(const u16* g, u16* l){
  __builtin_amdgcn_global_load_lds(
      (const __attribute__((address_space(1))) unsigned int*)(g),
      (__attribute__((address_space(3))) unsigned int*)(l), 16, 0, 0);
}

__global__ __launch_bounds__(256) void gemm_k(const u16* __restrict__ xb,
    const u16* __restrict__ wb, u16* __restrict__ phase0, float* __restrict__ amp0){
  __shared__ u16 lds[2][8192];          // [buf][16 KB]: A at 0, B at u16 4096
  const int tid = threadIdx.x;
  const int l   = tid & 63;
  const int w   = tid >> 6;

  const int bid = blockIdx.x;
  const int xcd = bid & 7;
  const int r   = bid >> 3;             // 0..87 within this XCD
  const int mt  = xcd * 8 + r / 11;
  const int nt  = r % 11;
  const int m0  = mt * 64;
  const int n0  = nt * 64;

  const int srow = w*16 + (l >> 3);
  const int scol = (((l & 7) ^ (l >> 3)) * 8);      // inverse-swizzled k-slot
  const u16* ga = xb + (size_t)(m0 + srow) * N_DIMS + scol;
  const u16* gb = wb + (size_t)(n0 + srow) * N_DIMS + scol;

  #define STAGE(b, kt) { \
    const u16* gA = ga + (kt)*64; \
    const u16* gB = gb + (kt)*64; \
    gload16(gA,            &lds[b][w*1024]); \
    gload16(gA + 8*N_DIMS, &lds[b][w*1024 + 512]); \
    gload16(gB,            &lds[b][4096 + w*1024]); \
    gload16(gB + 8*N_DIMS, &lds[b][4096 + w*1024 + 512]); }

  const int rl = l & 15;
  const int q0 = l >> 4;
  const int sx = l & 7;
  const int wr = w >> 1, wc = w & 1;

  f32x4 acc[2][2] = {};
  STAGE(0, 0)
  __syncthreads();

  for (int kt = 0; kt < 16; kt++){
    const int cb = kt & 1;
    if (kt < 15) STAGE(cb^1, kt+1)
    s16x8 a[2][2], b[2][2];
    #pragma unroll
    for (int mi = 0; mi < 2; mi++)
    #pragma unroll
    for (int ks = 0; ks < 2; ks++){
      int off = (wr*32 + mi*16 + rl)*64 + (((ks*4 + q0) ^ sx) * 8);
      a[mi][ks] = *(const s16x8*)&lds[cb][off];
    }
    #pragma unroll
    for (int nj = 0; nj < 2; nj++)
    #pragma unroll
    for (int ks = 0; ks < 2; ks++){
      int off = 4096 + (wc*32 + nj*16 + rl)*64 + (((ks*4 + q0) ^ sx) * 8);
      b[nj][ks] = *(const s16x8*)&lds[cb][off];
    }
    #pragma unroll
    for (int ks = 0; ks < 2; ks++)
    #pragma unroll
    for (int mi = 0; mi < 2; mi++)
    #pragma unroll
    for (int nj = 0; nj < 2; nj++)
      acc[mi][nj] = __builtin_amdgcn_mfma_f32_16x16x32_bf16(a[mi][ks], b[nj][ks], acc[mi][nj], 0,0,0);
    __syncthreads();
  }
  #undef STAGE

  // C/D layout: col = lane&15, row = (lane>>4)*4 + reg
  #pragma unroll
  for (int mi = 0; mi < 2; mi++)
  #pragma unroll
  for (int nj = 0; nj < 2; nj++){
    const int n = n0 + wc*32 + nj*16 + rl;
    #pragma unroll
    for (int rg = 0; rg < 4; rg++){
      const int m = m0 + wr*32 + mi*16 + q0*4 + rg;
      float v = acc[mi][nj][rg];
      if (n < N_OSC) { float t = v * INV2PI; t -= floorf(t); phase0[(size_t)m*N_OSC + n] = f2bf(t); }
      else           { amp0[(size_t)m*N_OSC + (n - N_OSC)] = fmaxf(fabsf(v), EPSV); }
    }
  }
}

// ---------------- iteration kernel (v2, bf16 phase0 input) ----------------
__device__ __forceinline__ int ibc(h2 v){ return __builtin_bit_cast(int, v); }
__device__ __forceinline__ h2  hbc(int v){ return __builtin_bit_cast(h2, v); }

__device__ __forceinline__ h2 rowsum16(h2 x){
  int v = ibc(x);
  v = ibc(hbc(v) + hbc(__builtin_amdgcn_mov_dpp(v, 0x121, 0xF, 0xF, true))); // row_ror:1
  v = ibc(hbc(v) + hbc(__builtin_amdgcn_mov_dpp(v, 0x122, 0xF, 0xF, true))); // row_ror:2
  v = ibc(hbc(v) + hbc(__builtin_amdgcn_mov_dpp(v, 0x124, 0xF, 0xF, true))); // row_ror:4
  v = ibc(hbc(v) + hbc(__builtin_amdgcn_mov_dpp(v, 0x128, 0xF, 0xF, true))); // row_ror:8
  return hbc(v);
}

__device__ __forceinline__ void updp(h2& s, h2& c, h2 cA, h2 sA, h2 GS, h2 GC){
  h2 e  = c*GS - s*GC;        // eps (radians), |e| <= 0.02
  h2 s1 = s*cA + c*sA;
  h2 c1 = c*cA - s*sA;
  s = s1 + c1*e;
  c = c1 - s1*e;
}

__device__ __forceinline__ h2 splat2(_Float16 v){ h2 r; r[0]=v; r[1]=v; return r; }

__global__ __launch_bounds__(256) void iter_k(const u16* __restrict__ phase0,
                                              float* __restrict__ amp){
  const int tid = threadIdx.x;
  const int l   = tid & 63;
  const int g   = l & 15;
  const int row = blockIdx.x*16 + (tid>>6)*4 + (l>>4);
  const size_t rb = (size_t)row * N_OSC;

  const h2 cAd = splat2((_Float16)0.99211470f), sAd = splat2((_Float16)0.12533323f);
  const h2 cAt = splat2((_Float16)0.92977649f), sAt = splat2((_Float16)0.36812455f);
  const h2 cAg = splat2((_Float16)-0.80901699f), sAg = splat2((_Float16)0.58778525f);
  const h2 kd = splat2((_Float16)6.25e-4f);    // DT*COUPLING/32
  const h2 kt = splat2((_Float16)3.125e-4f);   // /64
  const h2 kg = splat2((_Float16)7.8125e-5f);  // /256

  h2 sD, cD, sT[2], cT[2], sG[8], cG[8];
  {
    const u16* pr = phase0 + rb;
    unsigned dw = *(const unsigned*)(pr + 2*g);          // 2 bf16
    uint2 tw    = *(const uint2*)(pr + 32 + 4*g);        // 4 bf16
    uint4 g0w   = *(const uint4*)(pr + 96 + 16*g);       // 8 bf16
    uint4 g1w   = *(const uint4*)(pr + 96 + 16*g + 8);   // 8 bf16
    #define SC2(dS, dC, i, p0, p1) { \
      dS[i][0] = (_Float16)__builtin_amdgcn_sinf(p0); \
      dS[i][1] = (_Float16)__builtin_amdgcn_sinf(p1); \
      dC[i][0] = (_Float16)__builtin_amdgcn_cosf(p0); \
      dC[i][1] = (_Float16)__builtin_amdgcn_cosf(p1); }
    {
      float d0 = bf2f(dw & 0xFFFFu), d1 = bf2f(dw >> 16);
      sD[0] = (_Float16)__builtin_amdgcn_sinf(d0);
      sD[1] = (_Float16)__builtin_amdgcn_sinf(d1);
      cD[0] = (_Float16)__builtin_amdgcn_cosf(d0);
      cD[1] = (_Float16)__builtin_amdgcn_cosf(d1);
    }
    SC2(sT, cT, 0, bf2f(tw.x & 0xFFFFu), bf2f(tw.x >> 16))
    SC2(sT, cT, 1, bf2f(tw.y & 0xFFFFu), bf2f(tw.y >> 16))
    SC2(sG, cG, 0, bf2f(g0w.x & 0xFFFFu), bf2f(g0w.x >> 16))
    SC2(sG, cG, 1, bf2f(g0w.y & 0xFFFFu), bf2f(g0w.y >> 16))
    SC2(sG, cG, 2, bf2f(g0w.z & 0xFFFFu), bf2f(g0w.z >> 16))
    SC2(sG, cG, 3, bf2f(g0w.w & 0xFFFFu), bf2f(g0w.w >> 16))
    SC2(sG, cG, 4, bf2f(g1w.x & 0xFFFFu), bf2f(g1w.x >> 16))
    SC2(sG, cG, 5, bf2f(g1w.y & 0xFFFFu), bf2f(g1w.y >> 16))
    SC2(sG, cG, 6, bf2f(g1w.z & 0xFFFFu), bf2f(g1w.z >> 16))
    SC2(sG, cG, 7, bf2f(g1w.w & 0xFFFFu), bf2f(g1w.w >> 16))
    #undef SC2
  }

  h2 PD, PT, PG;
  #define REDUCE { \
    h2 pd; pd[0] = sD[0]+sD[1]; pd[1] = cD[0]+cD[1]; \
    h2 ts = sT[0]+sT[1], tc = cT[0]+cT[1]; \
    h2 pt; pt[0] = ts[0]+ts[1]; pt[1] = tc[0]+tc[1]; \
    h2 gs = ((sG[0]+sG[1])+(sG[2]+sG[3]))+((sG[4]+sG[5])+(sG[6]+sG[7])); \
    h2 gc = ((cG[0]+cG[1])+(cG[2]+cG[3]))+((cG[4]+cG[5])+(cG[6]+cG[7])); \
    h2 pg; pg[0] = gs[0]+gs[1]; pg[1] = gc[0]+gc[1]; \
    PD = rowsum16(pd); PT = rowsum16(pt); PG = rowsum16(pg); }

  REDUCE

  float Pth = 1.f, Pga = 1.f, mPth = 1.f, mPga = 1.f;
  for (int t = 0; t < 32; t++){
    h2 gd = PD * kd, gt = PT * kt, gg = PG * kg;   // (k*S, k*C)
    h2 GSd = splat2(gd[0]), GCd = splat2(gd[1]);
    h2 GSt = splat2(gt[0]), GCt = splat2(gt[1]);
    h2 GSg = splat2(gg[0]), GCg = splat2(gg[1]);
    updp(sD, cD, cAd, sAd, GSd, GCd);
    updp(sT[0], cT[0], cAt, sAt, GSt, GCt);
    updp(sT[1], cT[1], cAt, sAt, GSt, GCt);
    #pragma unroll
    for (int i = 0; i < 8; i++) updp(sG[i], cG[i], cAg, sAg, GSg, GCg);
    REDUCE
    float Sd = (float)PD[0], Cd = (float)PD[1];
    float St = (float)PT[0], Ct = (float)PT[1];
    float ft = 1.f + 0.003f * Cd * __builtin_amdgcn_rsqf(Cd*Cd + Sd*Sd);
    float fg = 1.f + 0.003f * Ct * __builtin_amdgcn_rsqf(Ct*Ct + St*St);
    Pth *= ft; mPth = fminf(mPth, Pth);
    Pga *= fg; mPga = fminf(mPga, Pga);
  }
  #undef REDUCE

  const float cth = EPSV * Pth / mPth;
  const float cga = EPSV * Pga / mPga;
  {
    float4 a = *(const float4*)(amp + rb + 32 + 4*g);
    a.x = fmaxf(a.x*Pth, cth); a.y = fmaxf(a.y*Pth, cth);
    a.z = fmaxf(a.z*Pth, cth); a.w = fmaxf(a.w*Pth, cth);
    *(float4*)(amp + rb + 32 + 4*g) = a;
  }
  #pragma unroll
  for (int i = 0; i < 4; i++){
    float4 a = *(const float4*)(amp + rb + 96 + 16*g + 4*i);
    a.x = fmaxf(a.x*Pga, cga); a.y = fmaxf(a.y*Pga, cga);
    a.z = fmaxf(a.z*Pga, cga); a.w = fmaxf(a.w*Pga, cga);
    *(float4*)(amp + rb + 96 + 16*g + 4*i) = a;
  }
}

// ---------------- launch ----------------
extern "C" void kernel_launch(void* const* d_in, const int* in_sizes, int n_in,
                              void* d_out, int out_size, void* d_ws, size_t ws_size,
                              hipStream_t stream){
  const float* x  = (const float*)d_in[0];
  const float* wp = (const float*)d_in[1];
  const float* wa = (const float*)d_in[2];
  float* out = (float*)d_out;
  char* ws = (char*)d_ws;
  u16* xb  = (u16*)(ws);                    // 8,388,608 B
  u16* wb  = (u16*)(ws + 8388608);          // 1,441,792 B
  u16* phase0 = (u16*)(ws + 9830400);       // 2,883,584 B (bf16)

  convert_k<<<4800, 256, 0, stream>>>((const f32x4*)x, (const f32x4*)wp, (const f32x4*)wa,
                                      (u16x4*)xb, (u16x4*)wb);
  gemm_k<<<704, 256, 0, stream>>>(xb, wb, phase0, out);
  iter_k<<<256, 256, 0, stream>>>(phase0, out);
}